// Round 7
// baseline (159.307 us; speedup 1.0000x reference)
//
#include <hip/hip_runtime.h>
#include <hip/hip_bf16.h>

#define BB 2
#define SS 513
#define HH 512
#define NHH 8
#define DDIM 64

__device__ __forceinline__ float dot4(float4 a, float4 b) {
  return a.x * b.x + a.y * b.y + a.z * b.z + a.w * b.w;
}
__device__ __forceinline__ float4 add4(float4 a, float4 b) {
  return make_float4(a.x + b.x, a.y + b.y, a.z + b.z, a.w + b.w);
}

// Sum over the 8-lane kg group (lanes l..l+7 share og) on the VALU pipe:
// quad_perm xor1, quad_perm xor2, then half-row mirror. All lanes get the sum.
#define DPP_ADD(v, ctrl) \
  ((v) + __int_as_float(__builtin_amdgcn_update_dpp( \
             0, __float_as_int(v), (ctrl), 0xF, 0xF, true)))
__device__ __forceinline__ float kg_reduce8(float v) {
  v = DPP_ADD(v, 0xB1);   // quad_perm [1,0,3,2]
  v = DPP_ADD(v, 0x4E);   // quad_perm [2,3,0,1]
  v = DPP_ADD(v, 0x141);  // row_half_mirror
  return v;
}

__device__ __forceinline__ bool graph_at(const void* g, int isBool, size_t idx) {
  if (isBool) return ((const unsigned char*)g)[idx] != 0;
  return ((const int*)g)[idx] != 0;
}

// ---------------------------------------------------------------------------
// Prep GEMV: loop-swapped, x cached in registers per k-chunk.
// grid = 3 tensors * 2 b * 68 row-chunks(8) = 408, block = 1024 (16 waves).
// Wave: 32 outputs (4 batches x 8 og); lane = (og = lane>>3, kg = lane&7).
// Per k-chunk i: 8 ds_read_b128 (x rows) feed 4 W-loads x 32 dot4.
__global__ __launch_bounds__(1024) void prep_kernel(
    const float* __restrict__ Xq, const float* __restrict__ Xk, const float* __restrict__ Xv,
    const float* __restrict__ Wq, const float* __restrict__ Wk, const float* __restrict__ Wv,
    const float* __restrict__ Bq, const float* __restrict__ Bk, const float* __restrict__ Bv,
    float* __restrict__ Yq, float* __restrict__ Yk, float* __restrict__ Yv) {
  __shared__ float xs[8][HH];  // 16 KB

  const int bid = blockIdx.x;
  const int unit = bid % 68;
  const int tb = bid / 68;
  const int tensor = tb >> 1, b = tb & 1;
  int f, chunk, count;
  if (unit < 24) { f = unit >> 3; chunk = unit & 7; count = 57; }
  else           { int u = unit - 24; f = 3 + u / 22; chunk = u % 22; count = 171; }

  const float* X  = (tensor == 0) ? Xq : (tensor == 1) ? Xk : Xv;
  const float* W  = (tensor == 0) ? Wq : (tensor == 1) ? Wk : Wv;
  const float* Bi = (tensor == 0) ? Bq : (tensor == 1) ? Bk : Bv;
  float* Y        = (tensor == 0) ? Yq : (tensor == 1) ? Yk : Yv;

  const int tid = threadIdx.x;

  // stage 8 rows: 1024 float4 loads, one per thread, coalesced
  {
    const int r = tid >> 7, c4 = (tid & 127) << 2;
    const int i = chunk * 8 + r;
    if (i < count) {
      const int t = (f < 3) ? (f + 9 * i) : (f + 2 * (i % 3) + 9 * (i / 3));
      *(float4*)&xs[r][c4] = *(const float4*)(X + (size_t)(b * SS + t) * HH + c4);
    }
  }
  __syncthreads();

  const int wid = tid >> 6, lane = tid & 63;
  const int og = lane >> 3, kg = lane & 7;
  const float* Wf = W + (size_t)f * HH * HH;
  const int o0 = wid * 32;
  const int kbase = kg * 4;

  float acc[4][8];
#pragma unroll
  for (int bt = 0; bt < 4; ++bt)
#pragma unroll
    for (int r = 0; r < 8; ++r) acc[bt][r] = 0.f;

#pragma unroll
  for (int i = 0; i < 16; ++i) {
    float4 x4[8];
#pragma unroll
    for (int r = 0; r < 8; ++r) x4[r] = *(const float4*)&xs[r][kbase + i * 32];
#pragma unroll
    for (int bt = 0; bt < 4; ++bt) {
      const float4 w4 =
          *(const float4*)(Wf + (size_t)(o0 + bt * 8 + og) * HH + kbase + i * 32);
#pragma unroll
      for (int r = 0; r < 8; ++r) acc[bt][r] += dot4(w4, x4[r]);
    }
  }

#pragma unroll
  for (int bt = 0; bt < 4; ++bt)
#pragma unroll
    for (int r = 0; r < 8; ++r) acc[bt][r] = kg_reduce8(acc[bt][r]);

  if (kg == 0) {
#pragma unroll
    for (int bt = 0; bt < 4; ++bt) {
      const int o = o0 + bt * 8 + og;
      float bs = 0.f;
#pragma unroll
      for (int ff = 0; ff < 5; ++ff) bs += Bi[ff * HH + o];
#pragma unroll
      for (int r = 0; r < 8; ++r) {
        int i = chunk * 8 + r;
        if (i < count) {
          int t = (f < 3) ? (f + 9 * i) : (f + 2 * (i % 3) + 9 * (i / 3));
          Y[(size_t)(b * SS + t) * HH + o] = acc[bt][r] + bs;
        }
      }
    }
  }
}

// ---------------------------------------------------------------------------
// Fused: blocks 0..31 = partial V-sum; block 32 = graph layout detect.
__global__ __launch_bounds__(256) void vsum_detect_kernel(
    const float* __restrict__ V, float* __restrict__ part,
    const uint4* __restrict__ gv, int* __restrict__ flag) {
  if (blockIdx.x < 32) {
    int idx = (blockIdx.x & 3) * 256 + threadIdx.x;
    int p = blockIdx.x >> 2;
    int b = idx >> 9, o = idx & 511;
    float acc = 0.f;
    for (int t = p; t < SS; t += 8)
      acc += V[(size_t)(b * SS + t) * HH + o];
    part[p * 1024 + idx] = acc;
  } else {
    __shared__ int s;
    if (threadIdx.x == 0) s = 0;
    __syncthreads();
    unsigned int local = 0;
    for (int i = threadIdx.x; i < 2048; i += 256) {  // 32 KB scan
      uint4 v = gv[i];
      local |= (v.x | v.y | v.z | v.w) & 0x0000ff00u;
    }
    if (local) atomicOr(&s, 1);
    __syncthreads();
    if (threadIdx.x == 0) *flag = s;
  }
}

// ---------------------------------------------------------------------------
// Fused attention: blocks [0,1020) sparse q>=3; blocks [1020,1836) dense scores.
__global__ __launch_bounds__(256) void attn_fused_kernel(
    const float* __restrict__ Q, const float* __restrict__ K, const float* __restrict__ V,
    const float* __restrict__ vsumPart, const void* __restrict__ graph,
    const int* __restrict__ flag,
    const float* __restrict__ EK, const float* __restrict__ EV, const float* __restrict__ EQ,
    float* __restrict__ X, float* __restrict__ sWS) {
  __shared__ float sQ[HH];
  __shared__ float sW[5 * NHH];
  __shared__ float sRed[4 * 64];
  __shared__ int sUni;

  const int tid = threadIdx.x, lane = tid & 63, wv = tid >> 6;
  const int isBool = *flag;

  if (blockIdx.x < 1020) {
    // ---------------- sparse path ----------------
    const int bid = blockIdx.x;
    const int b = bid / 510, q = 3 + bid % 510;
    const int row = b * SS + q;

    sQ[tid] = Q[(size_t)row * HH + tid];
    sQ[tid + 256] = Q[(size_t)row * HH + tid + 256];
    if (tid == 0) sUni = 0;
    __syncthreads();

    const int g = 3 + ((q - 3) >> 1) * 2;
    const size_t gbase = (size_t)b * SS * SS + (size_t)q * SS;
    const int h = lane >> 3, dg = lane & 7, d0 = dg * 8;

    for (int c = wv; c < 5; c += 4) {
      int k = (c < 3) ? c : g + (c - 3);
      bool m = graph_at(graph, isBool, gbase + k);
      const float* ekp = EK + (gbase + k) * DDIM + d0;
      const float* eqp = EQ + ((size_t)(b * SS + k) * SS + q) * DDIM + d0;
      const float* kp  = K + (size_t)(b * SS + k) * HH + h * 64 + d0;
      const float* qp  = &sQ[h * 64 + d0];
      float4 ek0 = *(const float4*)ekp, ek1 = *(const float4*)(ekp + 4);
      float4 eq0 = *(const float4*)eqp, eq1 = *(const float4*)(eqp + 4);
      float4 kk0 = *(const float4*)kp,  kk1 = *(const float4*)(kp + 4);
      float4 qq0 = *(const float4*)qp,  qq1 = *(const float4*)(qp + 4);
      float p = dot4(add4(qq0, eq0), add4(kk0, ek0)) + dot4(add4(qq1, eq1), add4(kk1, ek1));
      p += __shfl_xor(p, 1);
      p += __shfl_xor(p, 2);
      p += __shfl_xor(p, 4);
      if (dg == 0) sW[c * NHH + h] = m ? p * 0.125f : -1e30f;
    }
    __syncthreads();

    if (wv == 0) {
      int hh = lane >> 3, c = lane & 7;
      float s = (c < 5) ? sW[c * NHH + hh] : -1e30f;
      float mx = s;
#pragma unroll
      for (int off = 4; off; off >>= 1) mx = fmaxf(mx, __shfl_xor(mx, off));
      float e = (mx < -1e29f) ? 0.f : __expf(s - mx);
      float sum = e;
#pragma unroll
      for (int off = 4; off; off >>= 1) sum += __shfl_xor(sum, off);
      if (c < 5) sW[c * NHH + hh] = (mx < -1e29f) ? 0.f : e / sum;
      if (lane == 0 && mx < -1e29f) sUni = 1;
    }
    __syncthreads();

    if (sUni) {
      float acc = 0.f;
      for (int k = wv; k < SS; k += 4)
        acc += EV[(gbase + k) * DDIM + lane];
      sRed[wv * 64 + lane] = acc;
      __syncthreads();
      if (tid < 64) sRed[tid] = sRed[tid] + sRed[64 + tid] + sRed[128 + tid] + sRed[192 + tid];
      __syncthreads();
      const float c0 = 1.0f / 513.0f;
      for (int o = tid; o < HH; o += 256) {
        float vs = 0.f;
#pragma unroll
        for (int p = 0; p < 8; ++p) vs += vsumPart[p * 1024 + b * HH + o];
        X[(size_t)row * HH + o] = (vs + sRed[o & 63]) * c0;
      }
    } else {
#pragma unroll
      for (int rep = 0; rep < 2; ++rep) {
        int o = tid + rep * 256;
        int hh = o >> 6, d = o & 63;
        float acc = 0.f;
#pragma unroll
        for (int c = 0; c < 5; ++c) {
          int k = (c < 3) ? c : g + (c - 3);
          acc += sW[c * NHH + hh] *
                 (V[(size_t)(b * SS + k) * HH + o] + EV[(gbase + k) * DDIM + d]);
        }
        X[(size_t)row * HH + o] = acc;
      }
    }
  } else {
    // ---------------- dense score path (q < 3) ----------------
    const int bid = blockIdx.x - 1020;
    const int bqh = bid / 17, ks = bid % 17;
    const int b = bqh / 24, r = bqh % 24, q = r >> 3, hd = r & 7;
    const int kk = lane >> 3, dg = lane & 7, d0 = dg * 8;
    const int k = ks * 32 + wv * 8 + kk;
    const int kc = (k < SS) ? k : (SS - 1);
    const size_t gbase = (size_t)b * SS * SS + (size_t)q * SS;
    const bool m = (k < SS) && graph_at(graph, isBool, gbase + kc);

    const float* qp  = Q + (size_t)(b * SS + q) * HH + hd * 64 + d0;
    const float* ekp = EK + (gbase + kc) * DDIM + d0;
    const float* eqp = EQ + ((size_t)(b * SS + kc) * SS + q) * DDIM + d0;
    const float* kp  = K + (size_t)(b * SS + kc) * HH + hd * 64 + d0;
    float4 qq0 = *(const float4*)qp,  qq1 = *(const float4*)(qp + 4);
    float4 ek0 = *(const float4*)ekp, ek1 = *(const float4*)(ekp + 4);
    float4 eq0 = *(const float4*)eqp, eq1 = *(const float4*)(eqp + 4);
    float4 kk0 = *(const float4*)kp,  kk1 = *(const float4*)(kp + 4);
    float p = dot4(add4(qq0, eq0), add4(kk0, ek0)) + dot4(add4(qq1, eq1), add4(kk1, ek1));
    p += __shfl_xor(p, 1);
    p += __shfl_xor(p, 2);
    p += __shfl_xor(p, 4);
    if (dg == 0 && k < SS)
      sWS[(size_t)bqh * SS + k] = m ? p * 0.125f : -1e30f;
  }
}

// ---------------------------------------------------------------------------
// Dense finish: softmax + PV + combine, one block (1024 thr) per (b,q,h) = 48.
// All-masked row -> uniform 1/513 over ALL keys (matches jax softmax of -1e5 row).
__global__ __launch_bounds__(1024) void dense_finish_kernel(
    const float* __restrict__ V, const float* __restrict__ EV,
    const float* __restrict__ sWS, float* __restrict__ X) {
  __shared__ float red[16];
  __shared__ float sP[SS];
  __shared__ float sOut[16][DDIM];

  const int bqh = blockIdx.x;
  const int b = bqh / 24, r2 = bqh % 24, q = r2 >> 3, hd = r2 & 7;
  const int tid = threadIdx.x, lane = tid & 63, wv = tid >> 6;
  const float* s = sWS + (size_t)bqh * SS;

  const float v = (tid < SS) ? s[tid] : -3e38f;
  float mx = v;
#pragma unroll
  for (int off = 32; off; off >>= 1) mx = fmaxf(mx, __shfl_xor(mx, off));
  if (lane == 0) red[wv] = mx;
  __syncthreads();
  float mxAll = -3e38f;
#pragma unroll
  for (int j = 0; j < 16; ++j) mxAll = fmaxf(mxAll, red[j]);

  float p;
  if (mxAll < -1e29f) {
    p = 1.0f / 513.0f;  // uniform over all keys
  } else {
    float e = (tid < SS) ? __expf(v - mxAll) : 0.f;  // masked -1e30 underflows to 0
    float sm = e;
#pragma unroll
    for (int off = 32; off; off >>= 1) sm += __shfl_xor(sm, off);
    __syncthreads();  // red reuse (block-uniform branch)
    if (lane == 0) red[wv] = sm;
    __syncthreads();
    float tot = 0.f;
#pragma unroll
    for (int j = 0; j < 16; ++j) tot += red[j];
    p = e / tot;
  }
  if (tid < SS) sP[tid] = p;
  __syncthreads();

  // PV: thread = (k-chunk kc 0..15, d 0..63)
  const int d = tid & 63, kc = tid >> 6;
  const size_t evb = ((size_t)(b * SS + q) * SS) * DDIM;
  float acc = 0.f;
  for (int k = kc; k < SS; k += 16)
    acc += sP[k] * (V[(size_t)(b * SS + k) * HH + hd * 64 + d] +
                    EV[evb + (size_t)k * DDIM + d]);
  sOut[kc][d] = acc;
  __syncthreads();
  if (tid < 64) {
    float t = 0.f;
#pragma unroll
    for (int j = 0; j < 16; ++j) t += sOut[j][tid];
    X[(size_t)(b * SS + q) * HH + hd * 64 + tid] = t;
  }
}

// ---------------------------------------------------------------------------
// Output projection: loop-swapped, x-in-registers. grid = 129 chunks * 2 = 258,
// block = 1024 (16 waves). Wave: 16 outputs (2 batches x 8 og).
__global__ __launch_bounds__(1024) void proj_kernel(const float* __restrict__ Xin,
                                                    const float* __restrict__ Wo,
                                                    const float* __restrict__ bo,
                                                    float* __restrict__ out) {
  __shared__ float xs[8][HH];  // 16 KB

  const int chunk = blockIdx.x >> 1;
  const int oc = blockIdx.x & 1;
  const int tid = threadIdx.x;
  const int NROW = BB * SS;

  {
    const int r = tid >> 7, c4 = (tid & 127) << 2;
    const int row = chunk * 8 + r;
    if (row < NROW)
      *(float4*)&xs[r][c4] = *(const float4*)(Xin + (size_t)row * HH + c4);
  }
  __syncthreads();

  const int wid = tid >> 6, lane = tid & 63;
  const int og = lane >> 3, kg = lane & 7;
  const int o0 = oc * 256 + wid * 16;
  const int kbase = kg * 4;

  float acc[2][8];
#pragma unroll
  for (int bt = 0; bt < 2; ++bt)
#pragma unroll
    for (int r = 0; r < 8; ++r) acc[bt][r] = 0.f;

#pragma unroll
  for (int i = 0; i < 16; ++i) {
    float4 x4[8];
#pragma unroll
    for (int r = 0; r < 8; ++r) x4[r] = *(const float4*)&xs[r][kbase + i * 32];
#pragma unroll
    for (int bt = 0; bt < 2; ++bt) {
      const float4 w4 =
          *(const float4*)(Wo + (size_t)(o0 + bt * 8 + og) * HH + kbase + i * 32);
#pragma unroll
      for (int r = 0; r < 8; ++r) acc[bt][r] += dot4(w4, x4[r]);
    }
  }

#pragma unroll
  for (int bt = 0; bt < 2; ++bt)
#pragma unroll
    for (int r = 0; r < 8; ++r) acc[bt][r] = kg_reduce8(acc[bt][r]);

  if (kg == 0) {
#pragma unroll
    for (int bt = 0; bt < 2; ++bt) {
      const int o = o0 + bt * 8 + og;
      const float bias = bo[o];
#pragma unroll
      for (int r = 0; r < 8; ++r) {
        int row = chunk * 8 + r;
        if (row < NROW) out[(size_t)row * HH + o] = acc[bt][r] + bias;
      }
    }
  }
}

// ---------------------------------------------------------------------------
extern "C" void kernel_launch(void* const* d_in, const int* in_sizes, int n_in,
                              void* d_out, int out_size, void* d_ws, size_t ws_size,
                              hipStream_t stream) {
  (void)in_sizes; (void)n_in; (void)out_size; (void)ws_size;
  const float* query = (const float*)d_in[0];
  const float* key   = (const float*)d_in[1];
  const float* value = (const float*)d_in[2];
  const void*  graph = d_in[3];
  const float* EK = (const float*)d_in[4];
  const float* EV = (const float*)d_in[5];
  const float* EQ = (const float*)d_in[6];
  const float* Wq = (const float*)d_in[7];
  const float* bq = (const float*)d_in[8];
  const float* Wk = (const float*)d_in[9];
  const float* bk = (const float*)d_in[10];
  const float* Wv = (const float*)d_in[11];
  const float* bv = (const float*)d_in[12];
  const float* Wo = (const float*)d_in[13];
  const float* bo = (const float*)d_in[14];
  float* out = (float*)d_out;

  char* ws = (char*)d_ws;
  int*   flag = (int*)ws;                        // 4 B
  float* part = (float*)(ws + 256);              // 32 KB
  float* Qp = (float*)(ws + 40960);              // 2101248 B each
  float* Kp = (float*)(ws + 40960 + 2101248);
  float* Vp = (float*)(ws + 40960 + 2 * 2101248);
  float* Xp = (float*)(ws + 40960 + 3 * 2101248);
  float* sWS = (float*)(ws + 40960 + 4 * 2101248);  // 48*513*4 = 98496 B

  prep_kernel<<<408, 1024, 0, stream>>>(query, key, value, Wq, Wk, Wv, bq, bk, bv,
                                        Qp, Kp, Vp);
  vsum_detect_kernel<<<33, 256, 0, stream>>>(Vp, part, (const uint4*)graph, flag);
  attn_fused_kernel<<<1020 + 48 * 17, 256, 0, stream>>>(Qp, Kp, Vp, part, graph, flag,
                                                        EK, EV, EQ, Xp, sWS);
  dense_finish_kernel<<<48, 1024, 0, stream>>>(Vp, EV, sWS, Xp);
  proj_kernel<<<258, 1024, 0, stream>>>(Xp, Wo, bo, out);
}

// Round 8
// 156.088 us; speedup vs baseline: 1.0206x; 1.0206x over previous
//
#include <hip/hip_runtime.h>
#include <hip/hip_bf16.h>

#define BB 2
#define SS 513
#define HH 512
#define NHH 8
#define DDIM 64

__device__ __forceinline__ float dot4(float4 a, float4 b) {
  return a.x * b.x + a.y * b.y + a.z * b.z + a.w * b.w;
}
__device__ __forceinline__ float4 add4(float4 a, float4 b) {
  return make_float4(a.x + b.x, a.y + b.y, a.z + b.z, a.w + b.w);
}

// Sum over the 8-lane kg group (lanes l..l+7 share og) on the VALU pipe.
#define DPP_ADD(v, ctrl) \
  ((v) + __int_as_float(__builtin_amdgcn_update_dpp( \
             0, __float_as_int(v), (ctrl), 0xF, 0xF, true)))
__device__ __forceinline__ float kg_reduce8(float v) {
  v = DPP_ADD(v, 0xB1);   // quad_perm [1,0,3,2]
  v = DPP_ADD(v, 0x4E);   // quad_perm [2,3,0,1]
  v = DPP_ADD(v, 0x141);  // row_half_mirror
  return v;
}

__device__ __forceinline__ bool graph_at(const void* g, int isBool, size_t idx) {
  if (isBool) return ((const unsigned char*)g)[idx] != 0;
  return ((const int*)g)[idx] != 0;
}

// ---------------------------------------------------------------------------
// Prep GEMV, XCD-pinned: each (tensor,f) W slice is read by blocks on exactly
// one XCD (bid&7 assumed XCD round-robin), so each 1MB slice fills one L2 once.
// grid = 480 (8 xcd * 60 slots; some idle). block = 1024 (16 waves).
// xcd 0-5: slots 0..43 -> big combo (f>=3, 22 chunks x 2b); 44..59 -> one small.
// xcd 6: (2,0),(2,1); xcd 7: (2,2).
__global__ __launch_bounds__(1024) void prep_kernel(
    const float* __restrict__ Xq, const float* __restrict__ Xk, const float* __restrict__ Xv,
    const float* __restrict__ Wq, const float* __restrict__ Wk, const float* __restrict__ Wv,
    const float* __restrict__ Bq, const float* __restrict__ Bk, const float* __restrict__ Bv,
    float* __restrict__ Yq, float* __restrict__ Yk, float* __restrict__ Yv) {
  __shared__ float xs[8][HH];  // 16 KB

  const int xcd = blockIdx.x & 7;
  const int slot = blockIdx.x >> 3;
  int tensor, f, chunk, b;
  if (xcd < 6) {
    if (slot < 44) {
      tensor = xcd >> 1; f = 3 + (xcd & 1); b = slot / 22; chunk = slot % 22;
    } else {
      int ss = slot - 44;           // 0..15
      tensor = xcd / 3; f = xcd % 3; b = ss >> 3; chunk = ss & 7;
    }
  } else if (xcd == 6) {
    if (slot >= 32) return;
    tensor = 2; f = slot >> 4; b = (slot >> 3) & 1; chunk = slot & 7;
  } else {
    if (slot >= 16) return;
    tensor = 2; f = 2; b = slot >> 3; chunk = slot & 7;
  }
  const int count = (f < 3) ? 57 : 171;

  const float* X  = (tensor == 0) ? Xq : (tensor == 1) ? Xk : Xv;
  const float* W  = (tensor == 0) ? Wq : (tensor == 1) ? Wk : Wv;
  const float* Bi = (tensor == 0) ? Bq : (tensor == 1) ? Bk : Bv;
  float* Y        = (tensor == 0) ? Yq : (tensor == 1) ? Yk : Yv;

  const int tid = threadIdx.x;

  // stage 8 rows: 1024 float4 loads, one per thread, coalesced
  {
    const int r = tid >> 7, c4 = (tid & 127) << 2;
    const int i = chunk * 8 + r;
    if (i < count) {
      const int t = (f < 3) ? (f + 9 * i) : (f + 2 * (i % 3) + 9 * (i / 3));
      *(float4*)&xs[r][c4] = *(const float4*)(X + (size_t)(b * SS + t) * HH + c4);
    }
  }
  __syncthreads();

  const int wid = tid >> 6, lane = tid & 63;
  const int og = lane >> 3, kg = lane & 7;
  const float* Wf = W + (size_t)f * HH * HH;
  const int o0 = wid * 32;
  const int kbase = kg * 4;

  float acc[4][8];
#pragma unroll
  for (int bt = 0; bt < 4; ++bt)
#pragma unroll
    for (int r = 0; r < 8; ++r) acc[bt][r] = 0.f;

#pragma unroll
  for (int i = 0; i < 16; ++i) {
    float4 x4[8];
#pragma unroll
    for (int r = 0; r < 8; ++r) x4[r] = *(const float4*)&xs[r][kbase + i * 32];
#pragma unroll
    for (int bt = 0; bt < 4; ++bt) {
      const float4 w4 =
          *(const float4*)(Wf + (size_t)(o0 + bt * 8 + og) * HH + kbase + i * 32);
#pragma unroll
      for (int r = 0; r < 8; ++r) acc[bt][r] += dot4(w4, x4[r]);
    }
  }

#pragma unroll
  for (int bt = 0; bt < 4; ++bt)
#pragma unroll
    for (int r = 0; r < 8; ++r) acc[bt][r] = kg_reduce8(acc[bt][r]);

  if (kg == 0) {
#pragma unroll
    for (int bt = 0; bt < 4; ++bt) {
      const int o = o0 + bt * 8 + og;
      float bs = 0.f;
#pragma unroll
      for (int ff = 0; ff < 5; ++ff) bs += Bi[ff * HH + o];
#pragma unroll
      for (int r = 0; r < 8; ++r) {
        int i = chunk * 8 + r;
        if (i < count) {
          int t = (f < 3) ? (f + 9 * i) : (f + 2 * (i % 3) + 9 * (i / 3));
          Y[(size_t)(b * SS + t) * HH + o] = acc[bt][r] + bs;
        }
      }
    }
  }
}

// ---------------------------------------------------------------------------
// Fused: blocks 0..31 = partial V-sum; block 32 = graph layout detect.
__global__ __launch_bounds__(256) void vsum_detect_kernel(
    const float* __restrict__ V, float* __restrict__ part,
    const uint4* __restrict__ gv, int* __restrict__ flag) {
  if (blockIdx.x < 32) {
    int idx = (blockIdx.x & 3) * 256 + threadIdx.x;
    int p = blockIdx.x >> 2;
    int b = idx >> 9, o = idx & 511;
    float acc = 0.f;
    for (int t = p; t < SS; t += 8)
      acc += V[(size_t)(b * SS + t) * HH + o];
    part[p * 1024 + idx] = acc;
  } else {
    __shared__ int s;
    if (threadIdx.x == 0) s = 0;
    __syncthreads();
    unsigned int local = 0;
    for (int i = threadIdx.x; i < 2048; i += 256) {  // 32 KB scan
      uint4 v = gv[i];
      local |= (v.x | v.y | v.z | v.w) & 0x0000ff00u;
    }
    if (local) atomicOr(&s, 1);
    __syncthreads();
    if (threadIdx.x == 0) *flag = s;
  }
}

// ---------------------------------------------------------------------------
// Fused attention: blocks [0,1020) sparse q>=3; blocks [1020,1836) dense scores.
__global__ __launch_bounds__(256) void attn_fused_kernel(
    const float* __restrict__ Q, const float* __restrict__ K, const float* __restrict__ V,
    const float* __restrict__ vsumPart, const void* __restrict__ graph,
    const int* __restrict__ flag,
    const float* __restrict__ EK, const float* __restrict__ EV, const float* __restrict__ EQ,
    float* __restrict__ X, float* __restrict__ sWS) {
  __shared__ float sQ[HH];
  __shared__ float sW[5 * NHH];
  __shared__ float sRed[4 * 64];
  __shared__ int sUni;

  const int tid = threadIdx.x, lane = tid & 63, wv = tid >> 6;
  const int isBool = *flag;

  if (blockIdx.x < 1020) {
    // ---------------- sparse path ----------------
    const int bid = blockIdx.x;
    const int b = bid / 510, q = 3 + bid % 510;
    const int row = b * SS + q;

    sQ[tid] = Q[(size_t)row * HH + tid];
    sQ[tid + 256] = Q[(size_t)row * HH + tid + 256];
    if (tid == 0) sUni = 0;
    __syncthreads();

    const int g = 3 + ((q - 3) >> 1) * 2;
    const size_t gbase = (size_t)b * SS * SS + (size_t)q * SS;
    const int h = lane >> 3, dg = lane & 7, d0 = dg * 8;

    for (int c = wv; c < 5; c += 4) {
      int k = (c < 3) ? c : g + (c - 3);
      bool m = graph_at(graph, isBool, gbase + k);
      const float* ekp = EK + (gbase + k) * DDIM + d0;
      const float* eqp = EQ + ((size_t)(b * SS + k) * SS + q) * DDIM + d0;
      const float* kp  = K + (size_t)(b * SS + k) * HH + h * 64 + d0;
      const float* qp  = &sQ[h * 64 + d0];
      float4 ek0 = *(const float4*)ekp, ek1 = *(const float4*)(ekp + 4);
      float4 eq0 = *(const float4*)eqp, eq1 = *(const float4*)(eqp + 4);
      float4 kk0 = *(const float4*)kp,  kk1 = *(const float4*)(kp + 4);
      float4 qq0 = *(const float4*)qp,  qq1 = *(const float4*)(qp + 4);
      float p = dot4(add4(qq0, eq0), add4(kk0, ek0)) + dot4(add4(qq1, eq1), add4(kk1, ek1));
      p += __shfl_xor(p, 1);
      p += __shfl_xor(p, 2);
      p += __shfl_xor(p, 4);
      if (dg == 0) sW[c * NHH + h] = m ? p * 0.125f : -1e30f;
    }
    __syncthreads();

    if (wv == 0) {
      int hh = lane >> 3, c = lane & 7;
      float s = (c < 5) ? sW[c * NHH + hh] : -1e30f;
      float mx = s;
#pragma unroll
      for (int off = 4; off; off >>= 1) mx = fmaxf(mx, __shfl_xor(mx, off));
      float e = (mx < -1e29f) ? 0.f : __expf(s - mx);
      float sum = e;
#pragma unroll
      for (int off = 4; off; off >>= 1) sum += __shfl_xor(sum, off);
      if (c < 5) sW[c * NHH + hh] = (mx < -1e29f) ? 0.f : e / sum;
      if (lane == 0 && mx < -1e29f) sUni = 1;
    }
    __syncthreads();

    if (sUni) {
      float acc = 0.f;
      for (int k = wv; k < SS; k += 4)
        acc += EV[(gbase + k) * DDIM + lane];
      sRed[wv * 64 + lane] = acc;
      __syncthreads();
      if (tid < 64) sRed[tid] = sRed[tid] + sRed[64 + tid] + sRed[128 + tid] + sRed[192 + tid];
      __syncthreads();
      const float c0 = 1.0f / 513.0f;
      for (int o = tid; o < HH; o += 256) {
        float vs = 0.f;
#pragma unroll
        for (int p = 0; p < 8; ++p) vs += vsumPart[p * 1024 + b * HH + o];
        X[(size_t)row * HH + o] = (vs + sRed[o & 63]) * c0;
      }
    } else {
#pragma unroll
      for (int rep = 0; rep < 2; ++rep) {
        int o = tid + rep * 256;
        int hh = o >> 6, d = o & 63;
        float acc = 0.f;
#pragma unroll
        for (int c = 0; c < 5; ++c) {
          int k = (c < 3) ? c : g + (c - 3);
          acc += sW[c * NHH + hh] *
                 (V[(size_t)(b * SS + k) * HH + o] + EV[(gbase + k) * DDIM + d]);
        }
        X[(size_t)row * HH + o] = acc;
      }
    }
  } else {
    // ---------------- dense score path (q < 3) ----------------
    const int bid = blockIdx.x - 1020;
    const int bqh = bid / 17, ks = bid % 17;
    const int b = bqh / 24, r = bqh % 24, q = r >> 3, hd = r & 7;
    const int kk = lane >> 3, dg = lane & 7, d0 = dg * 8;
    const int k = ks * 32 + wv * 8 + kk;
    const int kc = (k < SS) ? k : (SS - 1);
    const size_t gbase = (size_t)b * SS * SS + (size_t)q * SS;
    const bool m = (k < SS) && graph_at(graph, isBool, gbase + kc);

    const float* qp  = Q + (size_t)(b * SS + q) * HH + hd * 64 + d0;
    const float* ekp = EK + (gbase + kc) * DDIM + d0;
    const float* eqp = EQ + ((size_t)(b * SS + kc) * SS + q) * DDIM + d0;
    const float* kp  = K + (size_t)(b * SS + kc) * HH + hd * 64 + d0;
    float4 qq0 = *(const float4*)qp,  qq1 = *(const float4*)(qp + 4);
    float4 ek0 = *(const float4*)ekp, ek1 = *(const float4*)(ekp + 4);
    float4 eq0 = *(const float4*)eqp, eq1 = *(const float4*)(eqp + 4);
    float4 kk0 = *(const float4*)kp,  kk1 = *(const float4*)(kp + 4);
    float p = dot4(add4(qq0, eq0), add4(kk0, ek0)) + dot4(add4(qq1, eq1), add4(kk1, ek1));
    p += __shfl_xor(p, 1);
    p += __shfl_xor(p, 2);
    p += __shfl_xor(p, 4);
    if (dg == 0 && k < SS)
      sWS[(size_t)bqh * SS + k] = m ? p * 0.125f : -1e30f;
  }
}

// ---------------------------------------------------------------------------
// Dense finish: softmax + PV + combine, one block (1024 thr) per (b,q,h) = 48.
__global__ __launch_bounds__(1024) void dense_finish_kernel(
    const float* __restrict__ V, const float* __restrict__ EV,
    const float* __restrict__ sWS, float* __restrict__ X) {
  __shared__ float red[16];
  __shared__ float sP[SS];
  __shared__ float sOut[16][DDIM];

  const int bqh = blockIdx.x;
  const int b = bqh / 24, r2 = bqh % 24, q = r2 >> 3, hd = r2 & 7;
  const int tid = threadIdx.x, lane = tid & 63, wv = tid >> 6;
  const float* s = sWS + (size_t)bqh * SS;

  const float v = (tid < SS) ? s[tid] : -3e38f;
  float mx = v;
#pragma unroll
  for (int off = 32; off; off >>= 1) mx = fmaxf(mx, __shfl_xor(mx, off));
  if (lane == 0) red[wv] = mx;
  __syncthreads();
  float mxAll = -3e38f;
#pragma unroll
  for (int j = 0; j < 16; ++j) mxAll = fmaxf(mxAll, red[j]);

  float p;
  if (mxAll < -1e29f) {
    p = 1.0f / 513.0f;  // uniform over all keys
  } else {
    float e = (tid < SS) ? __expf(v - mxAll) : 0.f;
    float sm = e;
#pragma unroll
    for (int off = 32; off; off >>= 1) sm += __shfl_xor(sm, off);
    __syncthreads();
    if (lane == 0) red[wv] = sm;
    __syncthreads();
    float tot = 0.f;
#pragma unroll
    for (int j = 0; j < 16; ++j) tot += red[j];
    p = e / tot;
  }
  if (tid < SS) sP[tid] = p;
  __syncthreads();

  const int d = tid & 63, kc = tid >> 6;
  const size_t evb = ((size_t)(b * SS + q) * SS) * DDIM;
  float acc = 0.f;
  for (int k = kc; k < SS; k += 16)
    acc += sP[k] * (V[(size_t)(b * SS + k) * HH + hd * 64 + d] +
                    EV[evb + (size_t)k * DDIM + d]);
  sOut[kc][d] = acc;
  __syncthreads();
  if (tid < 64) {
    float t = 0.f;
#pragma unroll
    for (int j = 0; j < 16; ++j) t += sOut[j][tid];
    X[(size_t)(b * SS + q) * HH + hd * 64 + tid] = t;
  }
}

// ---------------------------------------------------------------------------
// Output projection: loop-swapped, x-in-registers. grid = 258, block = 1024.
__global__ __launch_bounds__(1024) void proj_kernel(const float* __restrict__ Xin,
                                                    const float* __restrict__ Wo,
                                                    const float* __restrict__ bo,
                                                    float* __restrict__ out) {
  __shared__ float xs[8][HH];  // 16 KB

  const int chunk = blockIdx.x >> 1;
  const int oc = blockIdx.x & 1;
  const int tid = threadIdx.x;
  const int NROW = BB * SS;

  {
    const int r = tid >> 7, c4 = (tid & 127) << 2;
    const int row = chunk * 8 + r;
    if (row < NROW)
      *(float4*)&xs[r][c4] = *(const float4*)(Xin + (size_t)row * HH + c4);
  }
  __syncthreads();

  const int wid = tid >> 6, lane = tid & 63;
  const int og = lane >> 3, kg = lane & 7;
  const int o0 = oc * 256 + wid * 16;
  const int kbase = kg * 4;

  float acc[2][8];
#pragma unroll
  for (int bt = 0; bt < 2; ++bt)
#pragma unroll
    for (int r = 0; r < 8; ++r) acc[bt][r] = 0.f;

#pragma unroll
  for (int i = 0; i < 16; ++i) {
    float4 x4[8];
#pragma unroll
    for (int r = 0; r < 8; ++r) x4[r] = *(const float4*)&xs[r][kbase + i * 32];
#pragma unroll
    for (int bt = 0; bt < 2; ++bt) {
      const float4 w4 =
          *(const float4*)(Wo + (size_t)(o0 + bt * 8 + og) * HH + kbase + i * 32);
#pragma unroll
      for (int r = 0; r < 8; ++r) acc[bt][r] += dot4(w4, x4[r]);
    }
  }

#pragma unroll
  for (int bt = 0; bt < 2; ++bt)
#pragma unroll
    for (int r = 0; r < 8; ++r) acc[bt][r] = kg_reduce8(acc[bt][r]);

  if (kg == 0) {
#pragma unroll
    for (int bt = 0; bt < 2; ++bt) {
      const int o = o0 + bt * 8 + og;
      const float bias = bo[o];
#pragma unroll
      for (int r = 0; r < 8; ++r) {
        int row = chunk * 8 + r;
        if (row < NROW) out[(size_t)row * HH + o] = acc[bt][r] + bias;
      }
    }
  }
}

// ---------------------------------------------------------------------------
extern "C" void kernel_launch(void* const* d_in, const int* in_sizes, int n_in,
                              void* d_out, int out_size, void* d_ws, size_t ws_size,
                              hipStream_t stream) {
  (void)in_sizes; (void)n_in; (void)out_size; (void)ws_size;
  const float* query = (const float*)d_in[0];
  const float* key   = (const float*)d_in[1];
  const float* value = (const float*)d_in[2];
  const void*  graph = d_in[3];
  const float* EK = (const float*)d_in[4];
  const float* EV = (const float*)d_in[5];
  const float* EQ = (const float*)d_in[6];
  const float* Wq = (const float*)d_in[7];
  const float* bq = (const float*)d_in[8];
  const float* Wk = (const float*)d_in[9];
  const float* bk = (const float*)d_in[10];
  const float* Wv = (const float*)d_in[11];
  const float* bv = (const float*)d_in[12];
  const float* Wo = (const float*)d_in[13];
  const float* bo = (const float*)d_in[14];
  float* out = (float*)d_out;

  char* ws = (char*)d_ws;
  int*   flag = (int*)ws;                        // 4 B
  float* part = (float*)(ws + 256);              // 32 KB
  float* Qp = (float*)(ws + 40960);              // 2101248 B each
  float* Kp = (float*)(ws + 40960 + 2101248);
  float* Vp = (float*)(ws + 40960 + 2 * 2101248);
  float* Xp = (float*)(ws + 40960 + 3 * 2101248);
  float* sWS = (float*)(ws + 40960 + 4 * 2101248);  // 98496 B

  prep_kernel<<<480, 1024, 0, stream>>>(query, key, value, Wq, Wk, Wv, bq, bk, bv,
                                        Qp, Kp, Vp);
  vsum_detect_kernel<<<33, 256, 0, stream>>>(Vp, part, (const uint4*)graph, flag);
  attn_fused_kernel<<<1020 + 48 * 17, 256, 0, stream>>>(Qp, Kp, Vp, part, graph, flag,
                                                        EK, EV, EQ, Xp, sWS);
  dense_finish_kernel<<<48, 1024, 0, stream>>>(Vp, EV, sWS, Xp);
  proj_kernel<<<258, 1024, 0, stream>>>(Xp, Wo, bo, out);
}